// Round 8
// baseline (19.108 us; speedup 1.0000x reference)
//
#include <hip/hip_runtime.h>

#define N_ANCHORS 100000
#define BATCH 4
#define N_GT 64
#define PAIRS (N_ANCHORS / 2)   // N even -> pairs never split

typedef float v2f __attribute__((ext_vector_type(2)));

// Force VOP3P packed-fp32 ops (compiler won't form them from scalar IR).
// 8-byte operands with "v" constraint map to aligned VGPR pairs.
static __device__ __forceinline__ v2f pk_add(v2f a, v2f b) {
    v2f d; asm("v_pk_add_f32 %0, %1, %2" : "=v"(d) : "v"(a), "v"(b)); return d;
}
static __device__ __forceinline__ v2f pk_mul(v2f a, v2f b) {
    v2f d; asm("v_pk_mul_f32 %0, %1, %2" : "=v"(d) : "v"(a), "v"(b)); return d;
}

__global__ __launch_bounds__(256) void max_iou_kernel(
    const float4* __restrict__ anchors,
    const float4* __restrict__ gt,
    float* __restrict__ out)
{
    // gt staged as (-x1, -y1, x2, y2) + area.
    __shared__ float4 s_neg[N_GT];
    __shared__ float  s_ga[N_GT];

    const int tid = threadIdx.x;
    const int b = blockIdx.y;

    if (tid < N_GT) {
        const float4 g = gt[b * N_GT + tid];
        s_neg[tid] = make_float4(-g.x, -g.y, g.z, g.w);
        s_ga[tid]  = (g.z - g.x) * (g.w - g.y);
    }
    __syncthreads();

    const int p = blockIdx.x * blockDim.x + tid;
    const int i0 = 2 * p;
    if (i0 >= N_ANCHORS) return;

    const float4 a0 = anchors[i0];
    const float4 a1 = anchors[i0 + 1];

    const float a0xn = -a0.x, a0yn = -a0.y;
    const float a1xn = -a1.x, a1yn = -a1.y;
    const v2f area = {(a0.z - a0.x) * (a0.w - a0.y),
                      (a1.z - a1.x) * (a1.w - a1.y)};

    // Track t = inter / (areaA + areaG); iou = t/(1-t) is monotone in t.
    float t0 = 0.0f, t1 = 0.0f;

    #pragma unroll 8
    for (int g = 0; g < N_GT; ++g) {
        const float4 gb = s_neg[g];      // broadcast b128: (-gx1,-gy1,gx2,gy2)
        const float ga  = s_ga[g];       // broadcast b32

        const v2f S = pk_add(area, (v2f){ga, ga});          // 1 mov + 1 pk_add
        const float r0 = __builtin_amdgcn_rcpf(S.x);        // indep of inter
        const float r1 = __builtin_amdgcn_rcpf(S.y);

        // iw = min(az,gz) + min(-ax,-gx); ih = min(aw,gw) + min(-ay,-gy)
        const v2f min_zz = {fminf(a0.z, gb.z), fminf(a1.z, gb.z)};   // 2 v_min
        const v2f min_xx = {fminf(a0xn, gb.x), fminf(a1xn, gb.x)};   // 2 v_min
        const v2f min_ww = {fminf(a0.w, gb.w), fminf(a1.w, gb.w)};   // 2 v_min
        const v2f min_yy = {fminf(a0yn, gb.y), fminf(a1yn, gb.y)};   // 2 v_min
        const v2f iw0 = pk_add(min_zz, min_xx);
        const v2f ih  = pk_add(min_ww, min_yy);
        // Clamp iw only; ih<0 makes the candidate <=0, discarded by fmax(t>=0).
        const v2f iw  = {fmaxf(iw0.x, 0.0f), fmaxf(iw0.y, 0.0f)};    // 2 v_max
        const v2f cand = pk_mul(pk_mul(iw, ih), (v2f){r0, r1});
        t0 = fmaxf(t0, cand.x);                                      // 2 v_max
        t1 = fmaxf(t1, cand.y);
    }

    // iou = t/(1-t); t <= 1/2 so 1-t >= 1/2 (well-conditioned); t=0 -> 0.
    float2 res;
    res.x = t0 * __builtin_amdgcn_rcpf(1.0f - t0);
    res.y = t1 * __builtin_amdgcn_rcpf(1.0f - t1);
    *reinterpret_cast<float2*>(&out[b * N_ANCHORS + i0]) = res;   // 8B coalesced
}

extern "C" void kernel_launch(void* const* d_in, const int* in_sizes, int n_in,
                              void* d_out, int out_size, void* d_ws, size_t ws_size,
                              hipStream_t stream) {
    const float4* anchors = (const float4*)d_in[0];  // (100000, 4) fp32
    const float4* gt      = (const float4*)d_in[1];  // (4, 64, 4) fp32
    float* out            = (float*)d_out;           // (4, 100000) fp32

    dim3 grid((PAIRS + 255) / 256, BATCH);
    max_iou_kernel<<<grid, 256, 0, stream>>>(anchors, gt, out);
}

// Round 9
// 18.420 us; speedup vs baseline: 1.0373x; 1.0373x over previous
//
#include <hip/hip_runtime.h>

#define N_ANCHORS 100000
#define BATCH 4
#define N_GT 64
#define PAIRS (N_ANCHORS / 2)   // N even -> pairs never split

typedef float v2f __attribute__((ext_vector_type(2)));

__global__ __launch_bounds__(256) void max_iou_kernel(
    const float4* __restrict__ anchors,
    const float4* __restrict__ gt,
    float* __restrict__ out)
{
    // gt staged as (-x1, -y1, x2, y2) + area.
    __shared__ float4 s_neg[N_GT];
    __shared__ float  s_ga[N_GT];

    const int tid = threadIdx.x;
    const int b = blockIdx.y;

    if (tid < N_GT) {
        const float4 g = gt[b * N_GT + tid];
        s_neg[tid] = make_float4(-g.x, -g.y, g.z, g.w);
        s_ga[tid]  = (g.z - g.x) * (g.w - g.y);
    }
    __syncthreads();

    const int p = blockIdx.x * blockDim.x + tid;
    const int i0 = 2 * p;
    if (i0 >= N_ANCHORS) return;

    const float4 a0 = anchors[i0];
    const float4 a1 = anchors[i0 + 1];

    // Anchor pair with x1/y1 pre-negated: every subtract becomes an add.
    const v2f az  = {a0.z, a1.z};
    const v2f aw  = {a0.w, a1.w};
    const v2f axn = {-a0.x, -a1.x};
    const v2f ayn = {-a0.y, -a1.y};
    const v2f area = (az + axn) * (aw + ayn);

    // Track t = inter / (areaA + areaG); iou = t/(1-t) is monotone in t,
    // so max-iou == max-t, converted once at the end.  t in [0, 1/2].
    v2f t = {0.0f, 0.0f};

    #pragma unroll 8
    for (int g = 0; g < N_GT; ++g) {
        const float4 gb = s_neg[g];      // broadcast b128: (-gx1,-gy1,gx2,gy2)
        const float ga  = s_ga[g];       // broadcast b32
        const v2f S = area + ga;
        v2f r;
        r.x = __builtin_amdgcn_rcpf(S.x);   // independent of inter -> hides
        r.y = __builtin_amdgcn_rcpf(S.y);
        const v2f gz = {gb.z, gb.z}, gxn = {gb.x, gb.x};
        const v2f gw = {gb.w, gb.w}, gyn = {gb.y, gb.y};
        // iw = min(az,gz) - max(ax,gx) = min(az,gz) + min(-ax,-gx)
        const v2f iw0 = __builtin_elementwise_min(az, gz)
                      + __builtin_elementwise_min(axn, gxn);
        const v2f ih  = __builtin_elementwise_min(aw, gw)
                      + __builtin_elementwise_min(ayn, gyn);
        const v2f iw  = __builtin_elementwise_max(iw0, (v2f){0.0f, 0.0f});
        // ih < 0 -> candidate <= 0 -> discarded by the max (t >= 0): no clamp.
        t = __builtin_elementwise_max(t, iw * ih * r);
    }

    // iou = t/(1-t); t <= 1/2 so 1-t >= 1/2 (well-conditioned); t=0 -> 0.
    v2f invd;
    invd.x = __builtin_amdgcn_rcpf(1.0f - t.x);
    invd.y = __builtin_amdgcn_rcpf(1.0f - t.y);
    const v2f iou = t * invd;

    float2 res;
    res.x = iou.x;
    res.y = iou.y;
    *reinterpret_cast<float2*>(&out[b * N_ANCHORS + i0]) = res;   // 8B coalesced
}

extern "C" void kernel_launch(void* const* d_in, const int* in_sizes, int n_in,
                              void* d_out, int out_size, void* d_ws, size_t ws_size,
                              hipStream_t stream) {
    const float4* anchors = (const float4*)d_in[0];  // (100000, 4) fp32
    const float4* gt      = (const float4*)d_in[1];  // (4, 64, 4) fp32
    float* out            = (float*)d_out;           // (4, 100000) fp32

    dim3 grid((PAIRS + 255) / 256, BATCH);
    max_iou_kernel<<<grid, 256, 0, stream>>>(anchors, gt, out);
}